// Round 5
// baseline (30.644 us; speedup 1.0000x reference)
//
#include <hip/hip_runtime.h>

// GriddingReverse: grid (B=32, 64^3) f32 -> ptcloud (B, 64^3, 3) f32.
// Block = 1024 consecutive voxels (16 x-rows), 4 voxels/thread at +256 stride.
// Wave = one x-row per iteration: lane loads its own column's 4 corner rows,
// partial sums shared with the x-1 voxel via __shfl_up. 16 independent global
// loads in flight per thread (4x R3's MLP), one barrier per block, store phase
// = 256 lanes x 3 contiguous float4 (12KB span, all lines full).
// z & b are block-uniform; y = y0 + (t>>6) + 4*it, y0 multiple of 16 -> no wrap.

__global__ __launch_bounds__(256)
void GriddingReverse_kernel(const float* __restrict__ grid,
                            float* __restrict__ out)
{
    __shared__ float sm[3072];   // 1024 voxels * 3 floats

    int t = threadIdx.x;
    int blockBase = blockIdx.x << 10;
    int x  = t & 63;
    int yb = ((blockBase + t) >> 6) & 63;   // y for iteration 0
    int z  = (blockBase >> 12) & 63;        // block-uniform
    int b  = blockBase >> 18;               // block-uniform

    const float* __restrict__ g = grid + ((size_t)b << 18);
    const float sc = 2.0f / 64.0f;
    float fx = (float)(x - 1) - 32.0f;
    float fz = (float)(z - 1) - 32.0f;

    #pragma unroll
    for (int it = 0; it < 4; ++it) {
        int y = yb + (it << 2);
        float ox = 0.0f, oy = 0.0f, oz = 0.0f;

        if (z > 0 && y > 0) {               // wave-uniform
            int col = ((z - 1) << 12) + ((y - 1) << 6) + x;
            float a  = g[col];              // (z-1, y-1, x)
            float bv = g[col + 64];         // (z-1, y,   x)
            float c  = g[col + 4096];       // (z,   y-1, x)
            float d  = g[col + 4160];       // (z,   y,   x)

            float vv = c + d;               // wz1 column part
            float uu = bv + d;              // wy1 column part
            float ss = (a + bv) + vv;       // full column sum

            float sp = __shfl_up(ss, 1, 64);
            float up = __shfl_up(uu, 1, 64);
            float vp = __shfl_up(vv, 1, 64);

            if (x > 0) {
                float wsum = sp + ss;
                if (wsum > 0.0f) {
                    float inv = 1.0f / wsum;
                    ox = (fx + ss * inv) * sc;                       // wx1 = ss
                    oy = ((float)(y - 1) - 32.0f + (up + uu) * inv) * sc;
                    oz = (fz + (vp + vv) * inv) * sc;
                }
            }
        }

        int slot = (t + (it << 8)) * 3;
        sm[slot + 0] = ox;
        sm[slot + 1] = oy;
        sm[slot + 2] = oz;
    }
    __syncthreads();

    // Block output span: 3072 floats = 12KB, contiguous, 16B-aligned.
    const float4* s4 = reinterpret_cast<const float4*>(sm);
    float4* o4 = reinterpret_cast<float4*>(out + (size_t)blockBase * 3);
    #pragma unroll
    for (int i = 0; i < 3; ++i)
        o4[t + (i << 8)] = s4[t + (i << 8)];
}

extern "C" void kernel_launch(void* const* d_in, const int* in_sizes, int n_in,
                              void* d_out, int out_size, void* d_ws, size_t ws_size,
                              hipStream_t stream)
{
    const float* grid = (const float*)d_in[0];
    float* out = (float*)d_out;
    int total = in_sizes[0];            // B * 64^3 = 8,388,608 voxels
    int ngrid = total >> 10;            // 8192 blocks of 1024 voxels
    GriddingReverse_kernel<<<ngrid, 256, 0, stream>>>(grid, out);
}

// Round 7
// 26.319 us; speedup vs baseline: 1.1643x; 1.1643x over previous
//
#include <hip/hip_runtime.h>

// GriddingReverse: grid (B=32, 64^3) f32 -> ptcloud (B, 64^3, 3) f32.
// R3 structure (best: 26.3us): wave = x-row, lane loads own column's 4 corner
// rows, x-1 sums via __shfl_up. Changes vs R3:
//  - stores are nontemporal (nt): 100MB output is never re-read, keep it out
//    of L2 so the grid's 32MB read set stays resident.
//  - wave-local store staging: each wave stages its 192 floats in its own LDS
//    span and writes its own contiguous 768B (48 lanes x float4, 12 full
//    lines) -> no __syncthreads, waves fully independent.

typedef float f32x4 __attribute__((ext_vector_type(4)));

__global__ __launch_bounds__(256)
void GriddingReverse_kernel(const float* __restrict__ grid,
                            float* __restrict__ out)
{
    __shared__ float sm[768];   // 4 waves * 192 floats, wave-private spans

    int t = threadIdx.x;
    int idx = blockIdx.x * 256 + t;

    int x = idx & 63;
    int y = (idx >> 6) & 63;
    int z = (idx >> 12) & 63;
    int b = idx >> 18;

    float ox = 0.0f, oy = 0.0f, oz = 0.0f;

    if (y > 0 && z > 0) {                       // wave-uniform branch
        const float* __restrict__ g = grid + ((size_t)b << 18);
        int col = ((z - 1) << 12) + ((y - 1) << 6) + x;
        float a  = g[col];                      // (z-1, y-1, x)
        float bv = g[col + 64];                 // (z-1, y,   x)
        float c  = g[col + 4096];               // (z,   y-1, x)
        float d  = g[col + 4160];               // (z,   y,   x)

        float vv = c + d;                       // wz1 column part
        float uu = bv + d;                      // wy1 column part
        float ss = (a + bv) + vv;               // full column sum

        float sp = __shfl_up(ss, 1, 64);        // x-1 column from lane-1
        float up = __shfl_up(uu, 1, 64);
        float vp = __shfl_up(vv, 1, 64);

        if (x > 0) {
            float wsum = sp + ss;
            if (wsum > 0.0f) {
                float inv = 1.0f / wsum;
                const float s = 2.0f / 64.0f;
                ox = ((float)(x - 1) - 32.0f + ss * inv) * s;        // wx1 = ss
                oy = ((float)(y - 1) - 32.0f + (up + uu) * inv) * s; // wy1
                oz = ((float)(z - 1) - 32.0f + (vp + vv) * inv) * s; // wz1
            }
        }
    }

    // Wave-private LDS staging (same-wave write->read, no block barrier).
    sm[t * 3 + 0] = ox;
    sm[t * 3 + 1] = oy;
    sm[t * 3 + 2] = oz;
    __builtin_amdgcn_s_waitcnt(0);      // lgkmcnt(0): LDS writes visible
    __builtin_amdgcn_wave_barrier();    // keep wave-synchronous ordering

    int w    = t >> 6;                  // wave id
    int lane = t & 63;
    if (lane < 48) {
        const f32x4* s4 = reinterpret_cast<const f32x4*>(sm + w * 192);
        f32x4* o4 = reinterpret_cast<f32x4*>(out + (size_t)blockIdx.x * 768 + w * 192);
        __builtin_nontemporal_store(s4[lane], o4 + lane);
    }
}

extern "C" void kernel_launch(void* const* d_in, const int* in_sizes, int n_in,
                              void* d_out, int out_size, void* d_ws, size_t ws_size,
                              hipStream_t stream)
{
    const float* grid = (const float*)d_in[0];
    float* out = (float*)d_out;
    int total = in_sizes[0];            // B * 64^3 = 8,388,608 voxels
    int ngrid = total / 256;            // 32768 blocks
    GriddingReverse_kernel<<<ngrid, 256, 0, stream>>>(grid, out);
}